// Round 17
// baseline (337.473 us; speedup 1.0000x reference)
//
#include <hip/hip_runtime.h>
#include <hip/hip_bf16.h>

typedef short short8 __attribute__((ext_vector_type(8)));
typedef float f32x4 __attribute__((ext_vector_type(4)));

#define T_ 512
#define B_ 1024
#define D_ 128
#define H_ 64
#define A_ 18
#define TB_ (T_*B_)

#define XELEMS (TB_*H_)
#define WBASE  (2*XELEMS)
#define WBR    38912
#define W1OFF  0
#define W2OFF  8192
#define WIHOFF 12288
#define WHHOFF 24576
#define WHDOFF 36864

#define LOGN  (TB_*A_)
#define VOFF_ LOGN
#define SOFF_ (LOGN + TB_)

#define S1_ (-1.4426950408889634f)
#define S2_ (-2.885390081777927f)

__device__ __forceinline__ ushort f2bf(float f) {
  __hip_bfloat16 h = __float2bfloat16(f);
  return __builtin_bit_cast(ushort, h);
}
__device__ __forceinline__ uint cvt_pk_bf16(float lo, float hi) {
  uint r;
  asm("v_cvt_pk_bf16_f32 %0, %1, %2" : "=v"(r) : "v"(lo), "v"(hi));
  return r;
}
__device__ __forceinline__ ushort cvt1_bf16(float v) {
  return (ushort)(cvt_pk_bf16(v, v) & 0xffffu);
}
__device__ __forceinline__ f32x4 mfma16(short8 a, short8 b, f32x4 c) {
  return __builtin_amdgcn_mfma_f32_16x16x32_bf16(a, b, c, 0, 0, 0);
}

__global__ __launch_bounds__(256) void prep_kernel(
    const float* aW1, const float* aW2, const float* aWih, const float* aWhh, const float* aWl,
    const float* cW1, const float* cW2, const float* cWih, const float* cWhh, const float* cWv,
    ushort* wts) {
  int idx = blockIdx.x * 256 + threadIdx.x;
  if (idx >= 2*WBR) return;
  int br = idx / WBR, off = idx % WBR;
  float v;
  if      (off < W2OFF)  v = (br ? cW1  : aW1 )[off];
  else if (off < WIHOFF) v = (br ? cW2  : aW2 )[off - W2OFF];
  else if (off < WHHOFF) {
    int rel = off - WIHOFF;
    v = (br ? cWih : aWih)[rel];
    v *= (rel < 128*H_) ? S1_ : S2_;
  }
  else if (off < WHDOFF) {
    int rel = off - WHHOFF;
    v = (br ? cWhh : aWhh)[rel];
    v *= (rel < 128*H_) ? S1_ : S2_;
  }
  else {
    int t = off - WHDOFF;
    if (br == 0) v = (t < A_*H_) ? aWl[t] : 0.f;
    else         v = (t < H_)    ? cWv[t] : 0.f;
  }
  wts[WBASE + idx] = f2bf(v);
}

// ---- phase 1: MLP (weights in LDS, persistent 4-tile pipeline) -----------------------
__global__ __launch_bounds__(256) void mlp_kernel(
    const float* __restrict__ obs, const ushort* __restrict__ wts,
    const float* __restrict__ ab1, const float* __restrict__ ab2,
    const float* __restrict__ cb1, const float* __restrict__ cb2,
    ushort* __restrict__ xout) {
  __shared__ __align__(16) ushort htA[4][16 * H_], htC[4][16 * H_];
  __shared__ __align__(16) ushort wlds[24576];
  const int tid = threadIdx.x;
  const int l = tid & 63, w = tid >> 6;
  const int lr = l & 15, lg = l >> 4;
  const int key = lr & 7;
  const long base = (long)blockIdx.x * 256;
  const ushort* wbA = wts + WBASE;
  const ushort* wbC = wts + WBASE + WBR;

  float b1A[4], b1C[4], b2A[4], b2C[4];
  #pragma unroll
  for (int nt = 0; nt < 4; ++nt) {
    int coln = nt * 16 + lr;
    b1A[nt] = ab1[coln]; b1C[nt] = cb1[coln];
    b2A[nt] = ab2[coln]; b2C[nt] = cb2[coln];
  }

  #pragma unroll
  for (int i = 0; i < 12; ++i) {
    int c = tid + i * 256;
    int seg = (c < 1024) ? 0 : (c < 2048) ? 1 : (c < 2560) ? 2 : 3;
    int cbase = (seg == 0) ? 0 : (seg == 1) ? 1024 : (seg == 2) ? 2048 : 2560;
    int off = (c - cbase) * 8;
    int L = (seg < 2) ? 128 : 64;
    int segdst = (seg == 0) ? 0 : (seg == 1) ? 8192 : (seg == 2) ? 16384 : 20480;
    const ushort* src = (seg == 0) ? wbA + W1OFF + off :
                        (seg == 1) ? wbC + W1OFF + off :
                        (seg == 2) ? wbA + W2OFF + off : wbC + W2OFF + off;
    int n = off / L, ci = (off % L) / 8;
    int cis = (ci & ~7) | ((ci & 7) ^ (n & 7));
    *(uint4*)(wlds + segdst + n * L + cis * 8) = *(const uint4*)src;
  }
  __syncthreads();

  auto getW1 = [&](int br, int n, int ks) -> short8 {
    int ci = ks * 4 + lg;
    int cis = (ci & 8) | ((ci & 7) ^ (n & 7));
    return *(const short8*)(wlds + br * 8192 + n * D_ + cis * 8);
  };
  auto getW2 = [&](int br, int n, int ks) -> short8 {
    int ci = ks * 4 + lg;
    int cis = ci ^ (n & 7);
    return *(const short8*)(wlds + 16384 + br * 4096 + n * H_ + cis * 8);
  };

  auto ldobs = [&](int s, float4 (&buf)[8]) {
    const float* op = obs + (base + s * 64 + (long)w * 16 + lr) * D_;
    #pragma unroll
    for (int ks = 0; ks < 4; ++ks) {
      buf[2 * ks]     = *(const float4*)(op + ks * 32 + lg * 8);
      buf[2 * ks + 1] = *(const float4*)(op + ks * 32 + lg * 8 + 4);
    }
  };

  auto compute = [&](int s, float4 (&buf)[8]) {
    short8 af[4];
    #pragma unroll
    for (int ks = 0; ks < 4; ++ks) {
      uint4 u;
      u.x = cvt_pk_bf16(buf[2 * ks].x, buf[2 * ks].y);
      u.y = cvt_pk_bf16(buf[2 * ks].z, buf[2 * ks].w);
      u.z = cvt_pk_bf16(buf[2 * ks + 1].x, buf[2 * ks + 1].y);
      u.w = cvt_pk_bf16(buf[2 * ks + 1].z, buf[2 * ks + 1].w);
      af[ks] = __builtin_bit_cast(short8, u);
    }
    f32x4 aA[4], aC[4];
    #pragma unroll
    for (int nt = 0; nt < 4; ++nt) {
      aA[nt] = f32x4{b1A[nt], b1A[nt], b1A[nt], b1A[nt]};
      aC[nt] = f32x4{b1C[nt], b1C[nt], b1C[nt], b1C[nt]};
    }
    #pragma unroll
    for (int ks = 0; ks < 4; ++ks) {
      #pragma unroll
      for (int nt = 0; nt < 4; ++nt) {
        int n = nt * 16 + lr;
        aA[nt] = mfma16(af[ks], getW1(0, n, ks), aA[nt]);
        aC[nt] = mfma16(af[ks], getW1(1, n, ks), aC[nt]);
      }
    }
    #pragma unroll
    for (int nt = 0; nt < 4; ++nt) {
      int coln = nt * 16 + lr;
      #pragma unroll
      for (int j = 0; j < 4; ++j) {
        int rw = lg * 4 + j;
        int idx = rw * H_ + ((((coln >> 3) ^ (rw & 7))) << 3) + (coln & 7);
        htA[w][idx] = cvt1_bf16(fmaxf(aA[nt][j], 0.f));
        htC[w][idx] = cvt1_bf16(fmaxf(aC[nt][j], 0.f));
      }
    }
    short8 a2A[2], a2C[2];
    #pragma unroll
    for (int ks = 0; ks < 2; ++ks) {
      int c = ks * 4 + lg;
      a2A[ks] = *(const short8*)(&htA[w][lr * H_ + ((c ^ key) << 3)]);
      a2C[ks] = *(const short8*)(&htC[w][lr * H_ + ((c ^ key) << 3)]);
    }
    f32x4 cA[4], cC[4];
    #pragma unroll
    for (int nt = 0; nt < 4; ++nt) {
      cA[nt] = f32x4{b2A[nt], b2A[nt], b2A[nt], b2A[nt]};
      cC[nt] = f32x4{b2C[nt], b2C[nt], b2C[nt], b2C[nt]};
    }
    #pragma unroll
    for (int ks = 0; ks < 2; ++ks) {
      #pragma unroll
      for (int nt = 0; nt < 4; ++nt) {
        int n = nt * 16 + lr;
        cA[nt] = mfma16(a2A[ks], getW2(0, n, ks), cA[nt]);
        cC[nt] = mfma16(a2C[ks], getW2(1, n, ks), cC[nt]);
      }
    }
    #pragma unroll
    for (int nt = 0; nt < 4; ++nt) {
      int coln = nt * 16 + lr;
      #pragma unroll
      for (int j = 0; j < 4; ++j) {
        int rw = lg * 4 + j;
        int idx = rw * H_ + ((((coln >> 3) ^ (rw & 7))) << 3) + (coln & 7);
        htA[w][idx] = cvt1_bf16(fmaxf(cA[nt][j], 0.f));
        htC[w][idx] = cvt1_bf16(fmaxf(cC[nt][j], 0.f));
      }
    }
    {
      long rt = base + s * 64 + (long)w * 16;
      ushort* dpA = xout + (size_t)rt * H_;
      ushort* dpC = xout + (size_t)XELEMS + (size_t)rt * H_;
      #pragma unroll
      for (int i = 0; i < 2; ++i) {
        int id = l + i * 64;
        int rr = id >> 3, cc = id & 7;
        uint4 vA = *(const uint4*)(&htA[w][rr * H_ + ((cc ^ (rr & 7)) << 3)]);
        *(uint4*)(dpA + rr * H_ + (cc << 3)) = vA;
        uint4 vC = *(const uint4*)(&htC[w][rr * H_ + ((cc ^ (rr & 7)) << 3)]);
        *(uint4*)(dpC + rr * H_ + (cc << 3)) = vC;
      }
    }
  };

  float4 bufA[8], bufB[8];
  ldobs(0, bufA);
  ldobs(1, bufB);
  compute(0, bufA);
  ldobs(2, bufA);
  compute(1, bufB);
  ldobs(3, bufB);
  compute(2, bufA);
  compute(3, bufB);
}

// ---- phase 2: GRU scan, producer/consumer + fused heads ------------------------------
// waves 0-3 (consumer): recurrence; hands pre-reset h to producer via hhist LDS.
// waves 4-7 (producer): cpre(x_{t+1}), x prefetch, AND head (logits/values) for t-1
//   directly from hhist — h history never goes to HBM; head_kernel eliminated.
__global__ __launch_bounds__(512, 1) void scan_kernel(
    const ushort* __restrict__ wts,
    const ushort* __restrict__ xin,
    const float* __restrict__ dones,
    const float* __restrict__ astate, const float* __restrict__ cstate,
    const float* __restrict__ abih, const float* __restrict__ abhh,
    const float* __restrict__ cbih, const float* __restrict__ cbhh,
    const float* __restrict__ abl, const float* __restrict__ cbv,
    float* __restrict__ out) {
  __shared__ __align__(16) ushort hbuf[2][16 * H_];   // 4KB
  __shared__ __align__(8)  ushort dl16[T_ * 16];      // 16KB
  __shared__ __align__(16) float  preL[2][3][1024];   // 24KB
  __shared__ __align__(8)  uint2  hhist[2][256];      // 4KB
  const int tid = threadIdx.x;
  const int l = tid & 63, w = tid >> 6;
  const int pw = w & 3;
  const int lr = l & 15, lg = l >> 4;
  const int grp = blockIdx.x & 1;
  const int b0 = (blockIdx.x >> 1) * 16;
  const int slot = pw * 64 + ((l & ~7) | ((l ^ (l >> 3)) & 7));
  const int o4 = pw * 16 + lg * 4;

  const ushort* wb = wts + grp * WBR;
  const ushort* xp = xin + (size_t)grp * XELEMS;
  const float* bihp = grp ? cbih : abih;
  const float* bhhp = grp ? cbhh : abhh;
  const float* st   = grp ? cstate : astate;

  #pragma unroll
  for (int i = 0; i < 4; ++i) {
    int s = tid + i * 512;
    int t = s >> 2, p = s & 3;
    float4 v = *(const float4*)(dones + (size_t)t * B_ + b0 + p * 4);
    uint lo = (v.x != 0.f ? 1u : 0u) | ((v.y != 0.f ? 1u : 0u) << 16);
    uint hi = (v.z != 0.f ? 1u : 0u) | ((v.w != 0.f ? 1u : 0u) << 16);
    *(uint2*)(&dl16[t * 16 + p * 4]) = uint2{lo, hi};
  }

  // consumer state
  short8 hhW[3][2];
  f32x4 bhnv;
  float h_old[4];
  const int myW = lr * H_ + (((pw * 2 + (lg >> 1)) ^ (lr & 7)) << 3) + (lg & 1) * 4;
  const int rdA = lr * H_ + (((0 + lg) ^ (lr & 7)) << 3);
  const int rdB = lr * H_ + (((4 + lg) ^ (lr & 7)) << 3);

  // producer state
  short8 ihW[3][2];
  f32x4 bs0, bs1, binv;
  short8 pb0[2], pb1[2], pb2[2], pb3[2];
  short8 hdA[2][2];          // head weight A-frags (zero-padded to 32 rows)
  f32x4 hbias0, hbias1;      // head bias per output row

  auto loadx = [&](int t, short8 (&f)[2]) {
    const ushort* p = xp + ((size_t)t * B_ + b0 + lr) * H_;
    f[0] = *(const short8*)(p + lg * 8);
    f[1] = *(const short8*)(p + 32 + lg * 8);
  };
  auto cpre_to = [&](short8 (&xb)[2], int par) {
    f32x4 p0 = bs0, p1 = bs1, p2 = binv;
    p0 = mfma16(ihW[0][0], xb[0], p0); p0 = mfma16(ihW[0][1], xb[1], p0);
    p1 = mfma16(ihW[1][0], xb[0], p1); p1 = mfma16(ihW[1][1], xb[1], p1);
    p2 = mfma16(ihW[2][0], xb[0], p2); p2 = mfma16(ihW[2][1], xb[1], p2);
    *(f32x4*)&preL[par][0][slot * 4] = p0;
    *(f32x4*)&preL[par][1][slot * 4] = p1;
    *(f32x4*)&preL[par][2][slot * 4] = p2;
  };

  if (w < 4) {
    #pragma unroll
    for (int g = 0; g < 3; ++g) {
      int n = g * 64 + pw * 16 + lr;
      #pragma unroll
      for (int ks = 0; ks < 2; ++ks)
        hhW[g][ks] = *(const short8*)(wb + WHHOFF + n * H_ + ks * 32 + lg * 8);
    }
    float4 h2v = *(const float4*)(bhhp + 128 + o4);
    bhnv[0] = S2_ * h2v.x; bhnv[1] = S2_ * h2v.y;
    bhnv[2] = S2_ * h2v.z; bhnv[3] = S2_ * h2v.w;
    float4 h0v = *(const float4*)(st + (size_t)(b0 + lr) * H_ + o4);
    bool rs0 = (dones[b0 + lr] != 0.f);
    h_old[0] = rs0 ? 0.f : h0v.x; h_old[1] = rs0 ? 0.f : h0v.y;
    h_old[2] = rs0 ? 0.f : h0v.z; h_old[3] = rs0 ? 0.f : h0v.w;
    uint2 hv;
    hv.x = cvt_pk_bf16(h_old[0], h_old[1]);
    hv.y = cvt_pk_bf16(h_old[2], h_old[3]);
    *(uint2*)(&hbuf[0][myW]) = hv;
  } else {
    #pragma unroll
    for (int g = 0; g < 3; ++g) {
      int n = g * 64 + pw * 16 + lr;
      #pragma unroll
      for (int ks = 0; ks < 2; ++ks)
        ihW[g][ks] = *(const short8*)(wb + WIHOFF + n * H_ + ks * 32 + lg * 8);
    }
    float4 a0 = *(const float4*)(bihp + o4),       h0v = *(const float4*)(bhhp + o4);
    float4 a1 = *(const float4*)(bihp + 64 + o4),  h1v = *(const float4*)(bhhp + 64 + o4);
    float4 a2 = *(const float4*)(bihp + 128 + o4);
    bs0[0]=S1_*(a0.x+h0v.x); bs0[1]=S1_*(a0.y+h0v.y); bs0[2]=S1_*(a0.z+h0v.z); bs0[3]=S1_*(a0.w+h0v.w);
    bs1[0]=S1_*(a1.x+h1v.x); bs1[1]=S1_*(a1.y+h1v.y); bs1[2]=S1_*(a1.z+h1v.z); bs1[3]=S1_*(a1.w+h1v.w);
    binv[0]=S2_*a2.x; binv[1]=S2_*a2.y; binv[2]=S2_*a2.z; binv[3]=S2_*a2.w;
    // head weights + biases
    #pragma unroll
    for (int tile = 0; tile < 2; ++tile)
      #pragma unroll
      for (int ks = 0; ks < 2; ++ks)
        hdA[tile][ks] = *(const short8*)(wb + WHDOFF + (tile * 16 + lr) * H_ + ks * 32 + lg * 8);
    #pragma unroll
    for (int j = 0; j < 4; ++j) {
      int r0r = lg * 4 + j, r1r = 16 + lg * 4 + j;
      if (grp == 0) {
        hbias0[j] = (r0r < A_) ? abl[r0r] : 0.f;
        hbias1[j] = (r1r < A_) ? abl[r1r] : 0.f;
      } else {
        hbias0[j] = (r0r == 0) ? cbv[0] : 0.f;
        hbias1[j] = 0.f;
      }
    }
    loadx(0, pb0);
    cpre_to(pb0, 0);
    loadx(1, pb1); loadx(2, pb2); loadx(3, pb3); loadx(4, pb0);
  }

  __syncthreads();

  if (w < 4) {
    // =============================== consumer ===============================
    int cur = 0;
    auto cstep = [&](int t) {
      short8 hf0 = *(const short8*)(&hbuf[cur][rdA]);
      short8 hf1 = *(const short8*)(&hbuf[cur][rdB]);
      int par = t & 1;
      f32x4 S0 = *(const f32x4*)&preL[par][0][slot * 4];
      f32x4 S1 = *(const f32x4*)&preL[par][1][slot * 4];
      f32x4 P2 = *(const f32x4*)&preL[par][2][slot * 4];
      f32x4 Gh = bhnv;
      int tn = t + 1;
      ushort dn = dl16[((tn < T_) ? tn : 0) * 16 + lr];
      bool rs = (tn < T_) && (dn != 0);

      S0 = mfma16(hhW[0][0], hf0, S0); S0 = mfma16(hhW[0][1], hf1, S0);
      S1 = mfma16(hhW[1][0], hf0, S1); S1 = mfma16(hhW[1][1], hf1, S1);
      Gh = mfma16(hhW[2][0], hf0, Gh); Gh = mfma16(hhW[2][1], hf1, Gh);

      float hn[4];
      #pragma unroll
      for (int j = 0; j < 4; ++j) {
        // r = rcp(1+Er); sn = P2 + r*Gh; then single-rcp fused z/n update:
        // hn = (Ez + h + En*(h-Ez)) / (1 + En + Ez + En*Ez)
        float Er = __builtin_amdgcn_exp2f(S0[j]);
        float rr = __builtin_amdgcn_rcpf(1.f + Er);
        float Ez = __builtin_amdgcn_exp2f(S1[j]);
        float sn = fmaf(rr, Gh[j], P2[j]);
        float En = __builtin_amdgcn_exp2f(sn);
        float num = fmaf(En, h_old[j] - Ez, Ez + h_old[j]);
        float den = fmaf(En, Ez, 1.f + En + Ez);
        hn[j] = num * __builtin_amdgcn_rcpf(den);
      }
      uint2 hv;
      hv.x = cvt_pk_bf16(hn[0], hn[1]);
      hv.y = cvt_pk_bf16(hn[2], hn[3]);
      hhist[par][slot] = hv;                 // pre-reset h_t -> producer head
      uint2 hz;
      hz.x = rs ? 0u : hv.x;
      hz.y = rs ? 0u : hv.y;
      h_old[0] = rs ? 0.f : hn[0]; h_old[1] = rs ? 0.f : hn[1];
      h_old[2] = rs ? 0.f : hn[2]; h_old[3] = rs ? 0.f : hn[3];
      int nxt = cur ^ 1;
      *(uint2*)(&hbuf[nxt][myW]) = hz;
      asm volatile("s_waitcnt lgkmcnt(0)" ::: "memory");
      __builtin_amdgcn_s_barrier();
      cur = nxt;
    };
    for (int t = 0; t < T_; ++t) cstep(t);
    float4 fs = {h_old[0], h_old[1], h_old[2], h_old[3]};
    *(float4*)(out + SOFF_ + (size_t)grp * (B_ * H_) + (size_t)(b0 + lr) * H_ + o4) = fs;
  } else {
    // =============================== producer ===============================
    auto headstep = [&](int th) {          // logits/values for time th from hhist
      int par = th & 1;
      short8 hf[2];
      #pragma unroll
      for (int fr = 0; fr < 2; ++fr) {
        uint2 ua, ub;
        {
          int hcol = fr * 32 + lg * 8;
          int pw_s = hcol >> 4, lg_s = (hcol >> 2) & 3;
          int l_s = lg_s * 16 + lr;
          int sl = pw_s * 64 + ((l_s & ~7) | ((l_s ^ (l_s >> 3)) & 7));
          ua = hhist[par][sl];
        }
        {
          int hcol = fr * 32 + lg * 8 + 4;
          int pw_s = hcol >> 4, lg_s = (hcol >> 2) & 3;
          int l_s = lg_s * 16 + lr;
          int sl = pw_s * 64 + ((l_s & ~7) | ((l_s ^ (l_s >> 3)) & 7));
          ub = hhist[par][sl];
        }
        uint4 q = {ua.x, ua.y, ub.x, ub.y};
        hf[fr] = __builtin_bit_cast(short8, q);
      }
      f32x4 acc0 = hbias0, acc1 = hbias1;
      acc0 = mfma16(hdA[0][0], hf[0], acc0); acc0 = mfma16(hdA[0][1], hf[1], acc0);
      acc1 = mfma16(hdA[1][0], hf[0], acc1); acc1 = mfma16(hdA[1][1], hf[1], acc1);
      size_t rowb = (size_t)th * B_ + b0 + lr;     // batch = l&15
      if (grp == 0) {
        #pragma unroll
        for (int j = 0; j < 4; ++j) {
          int r0r = lg * 4 + j;
          out[rowb * A_ + r0r] = acc0[j];          // rows 0..15, always < 18
          int r1r = 16 + lg * 4 + j;
          if (r1r < A_) out[rowb * A_ + r1r] = acc1[j];
        }
      } else if (lg == 0) {
        out[VOFF_ + rowb] = acc0[0];               // value = row 0
      }
    };
    auto pstep = [&](int t, short8 (&xb)[2]) {
      if (t > 0) headstep(t - 1);
      if (t + 1 < T_) cpre_to(xb, (t + 1) & 1);
      if (t + 5 < T_) loadx(t + 5, xb);
      asm volatile("s_waitcnt lgkmcnt(0)" ::: "memory");
      __builtin_amdgcn_s_barrier();
    };
    for (int it = 0; it < T_ / 4; ++it) {
      int t = 4 * it;
      pstep(t,     pb1);
      pstep(t + 1, pb2);
      pstep(t + 2, pb3);
      pstep(t + 3, pb0);
    }
    headstep(T_ - 1);
  }
}

extern "C" void kernel_launch(void* const* d_in, const int* in_sizes, int n_in,
                              void* d_out, int out_size, void* d_ws, size_t ws_size,
                              hipStream_t stream) {
  const float* obs    = (const float*)d_in[0];
  const float* dones  = (const float*)d_in[1];
  const float* astate = (const float*)d_in[2];
  const float* cstate = (const float*)d_in[3];
  const float* aW1  = (const float*)d_in[4];
  const float* ab1  = (const float*)d_in[5];
  const float* aW2  = (const float*)d_in[6];
  const float* ab2  = (const float*)d_in[7];
  const float* aWih = (const float*)d_in[8];
  const float* aWhh = (const float*)d_in[9];
  const float* abih = (const float*)d_in[10];
  const float* abhh = (const float*)d_in[11];
  const float* aWl  = (const float*)d_in[12];
  const float* abl  = (const float*)d_in[13];
  const float* cW1  = (const float*)d_in[14];
  const float* cb1  = (const float*)d_in[15];
  const float* cW2  = (const float*)d_in[16];
  const float* cb2  = (const float*)d_in[17];
  const float* cWih = (const float*)d_in[18];
  const float* cWhh = (const float*)d_in[19];
  const float* cbih = (const float*)d_in[20];
  const float* cbhh = (const float*)d_in[21];
  const float* cWv  = (const float*)d_in[22];
  const float* cbv  = (const float*)d_in[23];
  ushort* ws = (ushort*)d_ws;
  float* out = (float*)d_out;

  const size_t need = ((size_t)2 * XELEMS + 2 * WBR) * 2;
  if (ws_size < need) {
    hipMemsetAsync(d_out, 0x7F, 16, stream);
    return;
  }

  hipLaunchKernelGGL(prep_kernel, dim3(304), dim3(256), 0, stream,
                     aW1, aW2, aWih, aWhh, aWl, cW1, cW2, cWih, cWhh, cWv, ws);
  hipLaunchKernelGGL(mlp_kernel, dim3(TB_ / 256), dim3(256), 0, stream,
                     obs, ws, ab1, ab2, cb1, cb2, ws);
  hipLaunchKernelGGL(scan_kernel, dim3(128), dim3(512), 0, stream,
                     ws + WBASE, ws, dones, astate, cstate,
                     abih, abhh, cbih, cbhh, abl, cbv, out);
}

// Round 18
// 327.466 us; speedup vs baseline: 1.0306x; 1.0306x over previous
//
#include <hip/hip_runtime.h>
#include <hip/hip_bf16.h>

typedef short short8 __attribute__((ext_vector_type(8)));
typedef float f32x4 __attribute__((ext_vector_type(4)));

#define T_ 512
#define B_ 1024
#define D_ 128
#define H_ 64
#define A_ 18
#define TB_ (T_*B_)

#define XELEMS (TB_*H_)
#define WBASE  (2*XELEMS)
#define WBR    38912
#define W1OFF  0
#define W2OFF  8192
#define WIHOFF 12288
#define WHHOFF 24576
#define WHDOFF 36864

#define LOGN  (TB_*A_)
#define VOFF_ LOGN
#define SOFF_ (LOGN + TB_)

#define S1_ (-1.4426950408889634f)
#define S2_ (-2.885390081777927f)

__device__ __forceinline__ ushort f2bf(float f) {
  __hip_bfloat16 h = __float2bfloat16(f);
  return __builtin_bit_cast(ushort, h);
}
__device__ __forceinline__ uint cvt_pk_bf16(float lo, float hi) {
  uint r;
  asm("v_cvt_pk_bf16_f32 %0, %1, %2" : "=v"(r) : "v"(lo), "v"(hi));
  return r;
}
__device__ __forceinline__ ushort cvt1_bf16(float v) {
  return (ushort)(cvt_pk_bf16(v, v) & 0xffffu);
}
__device__ __forceinline__ f32x4 mfma16(short8 a, short8 b, f32x4 c) {
  return __builtin_amdgcn_mfma_f32_16x16x32_bf16(a, b, c, 0, 0, 0);
}

__global__ __launch_bounds__(256) void prep_kernel(
    const float* aW1, const float* aW2, const float* aWih, const float* aWhh, const float* aWl,
    const float* cW1, const float* cW2, const float* cWih, const float* cWhh, const float* cWv,
    ushort* wts) {
  int idx = blockIdx.x * 256 + threadIdx.x;
  if (idx >= 2*WBR) return;
  int br = idx / WBR, off = idx % WBR;
  float v;
  if      (off < W2OFF)  v = (br ? cW1  : aW1 )[off];
  else if (off < WIHOFF) v = (br ? cW2  : aW2 )[off - W2OFF];
  else if (off < WHHOFF) {
    int rel = off - WIHOFF;
    v = (br ? cWih : aWih)[rel];
    v *= (rel < 128*H_) ? S1_ : S2_;
  }
  else if (off < WHDOFF) {
    int rel = off - WHHOFF;
    v = (br ? cWhh : aWhh)[rel];
    v *= (rel < 128*H_) ? S1_ : S2_;
  }
  else {
    int t = off - WHDOFF;
    if (br == 0) v = (t < A_*H_) ? aWl[t] : 0.f;
    else         v = (t < H_)    ? cWv[t] : 0.f;
  }
  wts[WBASE + idx] = f2bf(v);
}

// ---- phase 1: MLP (weights in LDS, persistent 4-tile pipeline) -----------------------
__global__ __launch_bounds__(256) void mlp_kernel(
    const float* __restrict__ obs, const ushort* __restrict__ wts,
    const float* __restrict__ ab1, const float* __restrict__ ab2,
    const float* __restrict__ cb1, const float* __restrict__ cb2,
    ushort* __restrict__ xout) {
  __shared__ __align__(16) ushort htA[4][16 * H_], htC[4][16 * H_];
  __shared__ __align__(16) ushort wlds[24576];
  const int tid = threadIdx.x;
  const int l = tid & 63, w = tid >> 6;
  const int lr = l & 15, lg = l >> 4;
  const int key = lr & 7;
  const long base = (long)blockIdx.x * 256;
  const ushort* wbA = wts + WBASE;
  const ushort* wbC = wts + WBASE + WBR;

  float b1A[4], b1C[4], b2A[4], b2C[4];
  #pragma unroll
  for (int nt = 0; nt < 4; ++nt) {
    int coln = nt * 16 + lr;
    b1A[nt] = ab1[coln]; b1C[nt] = cb1[coln];
    b2A[nt] = ab2[coln]; b2C[nt] = cb2[coln];
  }

  #pragma unroll
  for (int i = 0; i < 12; ++i) {
    int c = tid + i * 256;
    int seg = (c < 1024) ? 0 : (c < 2048) ? 1 : (c < 2560) ? 2 : 3;
    int cbase = (seg == 0) ? 0 : (seg == 1) ? 1024 : (seg == 2) ? 2048 : 2560;
    int off = (c - cbase) * 8;
    int L = (seg < 2) ? 128 : 64;
    int segdst = (seg == 0) ? 0 : (seg == 1) ? 8192 : (seg == 2) ? 16384 : 20480;
    const ushort* src = (seg == 0) ? wbA + W1OFF + off :
                        (seg == 1) ? wbC + W1OFF + off :
                        (seg == 2) ? wbA + W2OFF + off : wbC + W2OFF + off;
    int n = off / L, ci = (off % L) / 8;
    int cis = (ci & ~7) | ((ci & 7) ^ (n & 7));
    *(uint4*)(wlds + segdst + n * L + cis * 8) = *(const uint4*)src;
  }
  __syncthreads();

  auto getW1 = [&](int br, int n, int ks) -> short8 {
    int ci = ks * 4 + lg;
    int cis = (ci & 8) | ((ci & 7) ^ (n & 7));
    return *(const short8*)(wlds + br * 8192 + n * D_ + cis * 8);
  };
  auto getW2 = [&](int br, int n, int ks) -> short8 {
    int ci = ks * 4 + lg;
    int cis = ci ^ (n & 7);
    return *(const short8*)(wlds + 16384 + br * 4096 + n * H_ + cis * 8);
  };

  auto ldobs = [&](int s, float4 (&buf)[8]) {
    const float* op = obs + (base + s * 64 + (long)w * 16 + lr) * D_;
    #pragma unroll
    for (int ks = 0; ks < 4; ++ks) {
      buf[2 * ks]     = *(const float4*)(op + ks * 32 + lg * 8);
      buf[2 * ks + 1] = *(const float4*)(op + ks * 32 + lg * 8 + 4);
    }
  };

  auto compute = [&](int s, float4 (&buf)[8]) {
    short8 af[4];
    #pragma unroll
    for (int ks = 0; ks < 4; ++ks) {
      uint4 u;
      u.x = cvt_pk_bf16(buf[2 * ks].x, buf[2 * ks].y);
      u.y = cvt_pk_bf16(buf[2 * ks].z, buf[2 * ks].w);
      u.z = cvt_pk_bf16(buf[2 * ks + 1].x, buf[2 * ks + 1].y);
      u.w = cvt_pk_bf16(buf[2 * ks + 1].z, buf[2 * ks + 1].w);
      af[ks] = __builtin_bit_cast(short8, u);
    }
    f32x4 aA[4], aC[4];
    #pragma unroll
    for (int nt = 0; nt < 4; ++nt) {
      aA[nt] = f32x4{b1A[nt], b1A[nt], b1A[nt], b1A[nt]};
      aC[nt] = f32x4{b1C[nt], b1C[nt], b1C[nt], b1C[nt]};
    }
    #pragma unroll
    for (int ks = 0; ks < 4; ++ks) {
      #pragma unroll
      for (int nt = 0; nt < 4; ++nt) {
        int n = nt * 16 + lr;
        aA[nt] = mfma16(af[ks], getW1(0, n, ks), aA[nt]);
        aC[nt] = mfma16(af[ks], getW1(1, n, ks), aC[nt]);
      }
    }
    #pragma unroll
    for (int nt = 0; nt < 4; ++nt) {
      int coln = nt * 16 + lr;
      #pragma unroll
      for (int j = 0; j < 4; ++j) {
        int rw = lg * 4 + j;
        int idx = rw * H_ + ((((coln >> 3) ^ (rw & 7))) << 3) + (coln & 7);
        htA[w][idx] = cvt1_bf16(fmaxf(aA[nt][j], 0.f));
        htC[w][idx] = cvt1_bf16(fmaxf(aC[nt][j], 0.f));
      }
    }
    short8 a2A[2], a2C[2];
    #pragma unroll
    for (int ks = 0; ks < 2; ++ks) {
      int c = ks * 4 + lg;
      a2A[ks] = *(const short8*)(&htA[w][lr * H_ + ((c ^ key) << 3)]);
      a2C[ks] = *(const short8*)(&htC[w][lr * H_ + ((c ^ key) << 3)]);
    }
    f32x4 cA[4], cC[4];
    #pragma unroll
    for (int nt = 0; nt < 4; ++nt) {
      cA[nt] = f32x4{b2A[nt], b2A[nt], b2A[nt], b2A[nt]};
      cC[nt] = f32x4{b2C[nt], b2C[nt], b2C[nt], b2C[nt]};
    }
    #pragma unroll
    for (int ks = 0; ks < 2; ++ks) {
      #pragma unroll
      for (int nt = 0; nt < 4; ++nt) {
        int n = nt * 16 + lr;
        cA[nt] = mfma16(a2A[ks], getW2(0, n, ks), cA[nt]);
        cC[nt] = mfma16(a2C[ks], getW2(1, n, ks), cC[nt]);
      }
    }
    #pragma unroll
    for (int nt = 0; nt < 4; ++nt) {
      int coln = nt * 16 + lr;
      #pragma unroll
      for (int j = 0; j < 4; ++j) {
        int rw = lg * 4 + j;
        int idx = rw * H_ + ((((coln >> 3) ^ (rw & 7))) << 3) + (coln & 7);
        htA[w][idx] = cvt1_bf16(fmaxf(cA[nt][j], 0.f));
        htC[w][idx] = cvt1_bf16(fmaxf(cC[nt][j], 0.f));
      }
    }
    {
      long rt = base + s * 64 + (long)w * 16;
      ushort* dpA = xout + (size_t)rt * H_;
      ushort* dpC = xout + (size_t)XELEMS + (size_t)rt * H_;
      #pragma unroll
      for (int i = 0; i < 2; ++i) {
        int id = l + i * 64;
        int rr = id >> 3, cc = id & 7;
        uint4 vA = *(const uint4*)(&htA[w][rr * H_ + ((cc ^ (rr & 7)) << 3)]);
        *(uint4*)(dpA + rr * H_ + (cc << 3)) = vA;
        uint4 vC = *(const uint4*)(&htC[w][rr * H_ + ((cc ^ (rr & 7)) << 3)]);
        *(uint4*)(dpC + rr * H_ + (cc << 3)) = vC;
      }
    }
  };

  float4 bufA[8], bufB[8];
  ldobs(0, bufA);
  ldobs(1, bufB);
  compute(0, bufA);
  ldobs(2, bufA);
  compute(1, bufB);
  ldobs(3, bufB);
  compute(2, bufA);
  compute(3, bufB);
}

// ---- phase 2: GRU scan, producer/consumer (R16 structure, fused z/n gate math) -------
__global__ __launch_bounds__(512, 1) void scan_kernel(
    const ushort* __restrict__ wts,
    const ushort* __restrict__ xin,     // load-only view of x region
    ushort* __restrict__ hist,          // store-only view (t-disjoint vs loads)
    const float* __restrict__ dones,
    const float* __restrict__ astate, const float* __restrict__ cstate,
    const float* __restrict__ abih, const float* __restrict__ abhh,
    const float* __restrict__ cbih, const float* __restrict__ cbhh,
    float* __restrict__ out) {
  __shared__ __align__(16) ushort hbuf[2][16 * H_];   // 4KB
  __shared__ __align__(8)  ushort dl16[T_ * 16];      // 16KB
  __shared__ __align__(16) float  preL[2][3][1024];   // 24KB
  __shared__ __align__(8)  uint2  hhist[2][256];      // 4KB
  const int tid = threadIdx.x;
  const int l = tid & 63, w = tid >> 6;
  const int pw = w & 3;
  const int lr = l & 15, lg = l >> 4;
  const int grp = blockIdx.x & 1;
  const int b0 = (blockIdx.x >> 1) * 16;
  const int slot = pw * 64 + ((l & ~7) | ((l ^ (l >> 3)) & 7));
  const int o4 = pw * 16 + lg * 4;

  const ushort* wb = wts + grp * WBR;
  const ushort* xp = xin + (size_t)grp * XELEMS;
  ushort* hp = hist + (size_t)grp * XELEMS;
  const float* bihp = grp ? cbih : abih;
  const float* bhhp = grp ? cbhh : abhh;
  const float* st   = grp ? cstate : astate;

  #pragma unroll
  for (int i = 0; i < 4; ++i) {
    int s = tid + i * 512;
    int t = s >> 2, p = s & 3;
    float4 v = *(const float4*)(dones + (size_t)t * B_ + b0 + p * 4);
    uint lo = (v.x != 0.f ? 1u : 0u) | ((v.y != 0.f ? 1u : 0u) << 16);
    uint hi = (v.z != 0.f ? 1u : 0u) | ((v.w != 0.f ? 1u : 0u) << 16);
    *(uint2*)(&dl16[t * 16 + p * 4]) = uint2{lo, hi};
  }

  // consumer state
  short8 hhW[3][2];
  f32x4 bhnv;
  float h_old[4];
  const int myW = lr * H_ + (((pw * 2 + (lg >> 1)) ^ (lr & 7)) << 3) + (lg & 1) * 4;
  const int rdA = lr * H_ + (((0 + lg) ^ (lr & 7)) << 3);
  const int rdB = lr * H_ + (((4 + lg) ^ (lr & 7)) << 3);

  // producer state
  short8 ihW[3][2];
  f32x4 bs0, bs1, binv;
  short8 pb0[2], pb1[2], pb2[2], pb3[2];

  auto loadx = [&](int t, short8 (&f)[2]) {
    const ushort* p = xp + ((size_t)t * B_ + b0 + lr) * H_;
    f[0] = *(const short8*)(p + lg * 8);
    f[1] = *(const short8*)(p + 32 + lg * 8);
  };
  auto cpre_to = [&](short8 (&xb)[2], int par) {
    f32x4 p0 = bs0, p1 = bs1, p2 = binv;
    p0 = mfma16(ihW[0][0], xb[0], p0); p0 = mfma16(ihW[0][1], xb[1], p0);
    p1 = mfma16(ihW[1][0], xb[0], p1); p1 = mfma16(ihW[1][1], xb[1], p1);
    p2 = mfma16(ihW[2][0], xb[0], p2); p2 = mfma16(ihW[2][1], xb[1], p2);
    *(f32x4*)&preL[par][0][slot * 4] = p0;
    *(f32x4*)&preL[par][1][slot * 4] = p1;
    *(f32x4*)&preL[par][2][slot * 4] = p2;
  };

  if (w < 4) {
    #pragma unroll
    for (int g = 0; g < 3; ++g) {
      int n = g * 64 + pw * 16 + lr;
      #pragma unroll
      for (int ks = 0; ks < 2; ++ks)
        hhW[g][ks] = *(const short8*)(wb + WHHOFF + n * H_ + ks * 32 + lg * 8);
    }
    float4 h2v = *(const float4*)(bhhp + 128 + o4);
    bhnv[0] = S2_ * h2v.x; bhnv[1] = S2_ * h2v.y;
    bhnv[2] = S2_ * h2v.z; bhnv[3] = S2_ * h2v.w;
    float4 h0v = *(const float4*)(st + (size_t)(b0 + lr) * H_ + o4);
    bool rs0 = (dones[b0 + lr] != 0.f);
    h_old[0] = rs0 ? 0.f : h0v.x; h_old[1] = rs0 ? 0.f : h0v.y;
    h_old[2] = rs0 ? 0.f : h0v.z; h_old[3] = rs0 ? 0.f : h0v.w;
    uint2 hv;
    hv.x = cvt_pk_bf16(h_old[0], h_old[1]);
    hv.y = cvt_pk_bf16(h_old[2], h_old[3]);
    *(uint2*)(&hbuf[0][myW]) = hv;
  } else {
    #pragma unroll
    for (int g = 0; g < 3; ++g) {
      int n = g * 64 + pw * 16 + lr;
      #pragma unroll
      for (int ks = 0; ks < 2; ++ks)
        ihW[g][ks] = *(const short8*)(wb + WIHOFF + n * H_ + ks * 32 + lg * 8);
    }
    float4 a0 = *(const float4*)(bihp + o4),       h0v = *(const float4*)(bhhp + o4);
    float4 a1 = *(const float4*)(bihp + 64 + o4),  h1v = *(const float4*)(bhhp + 64 + o4);
    float4 a2 = *(const float4*)(bihp + 128 + o4);
    bs0[0]=S1_*(a0.x+h0v.x); bs0[1]=S1_*(a0.y+h0v.y); bs0[2]=S1_*(a0.z+h0v.z); bs0[3]=S1_*(a0.w+h0v.w);
    bs1[0]=S1_*(a1.x+h1v.x); bs1[1]=S1_*(a1.y+h1v.y); bs1[2]=S1_*(a1.z+h1v.z); bs1[3]=S1_*(a1.w+h1v.w);
    binv[0]=S2_*a2.x; binv[1]=S2_*a2.y; binv[2]=S2_*a2.z; binv[3]=S2_*a2.w;
    loadx(0, pb0);
    cpre_to(pb0, 0);
    loadx(1, pb1); loadx(2, pb2); loadx(3, pb3); loadx(4, pb0);
  }

  __syncthreads();

  if (w < 4) {
    // =============================== consumer ===============================
    int cur = 0;
    auto cstep = [&](int t) {
      short8 hf0 = *(const short8*)(&hbuf[cur][rdA]);
      short8 hf1 = *(const short8*)(&hbuf[cur][rdB]);
      int par = t & 1;
      f32x4 S0 = *(const f32x4*)&preL[par][0][slot * 4];
      f32x4 S1 = *(const f32x4*)&preL[par][1][slot * 4];
      f32x4 P2 = *(const f32x4*)&preL[par][2][slot * 4];
      f32x4 Gh = bhnv;
      int tn = t + 1;
      ushort dn = dl16[((tn < T_) ? tn : 0) * 16 + lr];
      bool rs = (tn < T_) && (dn != 0);

      S0 = mfma16(hhW[0][0], hf0, S0); S0 = mfma16(hhW[0][1], hf1, S0);
      S1 = mfma16(hhW[1][0], hf0, S1); S1 = mfma16(hhW[1][1], hf1, S1);
      Gh = mfma16(hhW[2][0], hf0, Gh); Gh = mfma16(hhW[2][1], hf1, Gh);

      float hn[4];
      #pragma unroll
      for (int j = 0; j < 4; ++j) {
        // r = rcp(1+Er); sn = P2 + r*Gh; fused z/n update (exact rewrite):
        // hn = (Ez + h + En*(h-Ez)) / (1 + En + Ez + En*Ez)
        float Er = __builtin_amdgcn_exp2f(S0[j]);
        float rr = __builtin_amdgcn_rcpf(1.f + Er);
        float Ez = __builtin_amdgcn_exp2f(S1[j]);
        float sn = fmaf(rr, Gh[j], P2[j]);
        float En = __builtin_amdgcn_exp2f(sn);
        float num = fmaf(En, h_old[j] - Ez, Ez + h_old[j]);
        float den = fmaf(En, Ez, 1.f + En + Ez);
        hn[j] = num * __builtin_amdgcn_rcpf(den);
      }
      uint2 hv;
      hv.x = cvt_pk_bf16(hn[0], hn[1]);
      hv.y = cvt_pk_bf16(hn[2], hn[3]);
      hhist[par][slot] = hv;                 // pre-reset h_t -> producer history store
      uint2 hz;
      hz.x = rs ? 0u : hv.x;
      hz.y = rs ? 0u : hv.y;
      h_old[0] = rs ? 0.f : hn[0]; h_old[1] = rs ? 0.f : hn[1];
      h_old[2] = rs ? 0.f : hn[2]; h_old[3] = rs ? 0.f : hn[3];
      int nxt = cur ^ 1;
      *(uint2*)(&hbuf[nxt][myW]) = hz;
      asm volatile("s_waitcnt lgkmcnt(0)" ::: "memory");
      __builtin_amdgcn_s_barrier();
      cur = nxt;
    };
    for (int t = 0; t < T_; ++t) cstep(t);
    float4 fs = {h_old[0], h_old[1], h_old[2], h_old[3]};
    *(float4*)(out + SOFF_ + (size_t)grp * (B_ * H_) + (size_t)(b0 + lr) * H_ + o4) = fs;
  } else {
    // =============================== producer ===============================
    auto pstep = [&](int t, short8 (&xb)[2]) {
      if (t > 0) {
        uint2 hv2 = hhist[(t - 1) & 1][slot];
        *(uint2*)(hp + ((size_t)(t - 1) * B_ + b0 + lr) * H_ + o4) = hv2;
      }
      if (t + 1 < T_) cpre_to(xb, (t + 1) & 1);
      if (t + 5 < T_) loadx(t + 5, xb);
      asm volatile("s_waitcnt lgkmcnt(0)" ::: "memory");
      __builtin_amdgcn_s_barrier();
    };
    for (int it = 0; it < T_ / 4; ++it) {
      int t = 4 * it;
      pstep(t,     pb1);
      pstep(t + 1, pb2);
      pstep(t + 2, pb3);
      pstep(t + 3, pb0);
    }
    uint2 hv2 = hhist[(T_ - 1) & 1][slot];
    *(uint2*)(hp + ((size_t)(T_ - 1) * B_ + b0 + lr) * H_ + o4) = hv2;
  }
}

// ---------------- phase 3: heads --------------------------------------------------------
__global__ __launch_bounds__(256) void head_kernel(
    const ushort* __restrict__ ws,
    const float* __restrict__ abl, const float* __restrict__ cbv,
    float* __restrict__ out) {
  __shared__ float ltile[4][16 * A_];
  const int tid = threadIdx.x;
  const int l = tid & 63, w = tid >> 6;
  const int lr = l & 15, lg = l >> 4;
  const long r0 = (long)blockIdx.x * 64 + w * 16;
  const f32x4 fzero = {0.f, 0.f, 0.f, 0.f};

  const ushort* hA = ws + r0 * H_;
  const ushort* hC = ws + XELEMS + r0 * H_;
  short8 aA[2], aC[2];
  #pragma unroll
  for (int ks = 0; ks < 2; ++ks) {
    aA[ks] = *(const short8*)(hA + lr * H_ + ks * 32 + lg * 8);
    aC[ks] = *(const short8*)(hC + lr * H_ + ks * 32 + lg * 8);
  }
  const ushort* wbA = ws + WBASE + WHDOFF;
  const ushort* wbC = ws + WBASE + WBR + WHDOFF;
  f32x4 acc[2];
  acc[0] = fzero; acc[1] = fzero;
  #pragma unroll
  for (int nt = 0; nt < 2; ++nt) {
    int n = nt * 16 + lr;
    #pragma unroll
    for (int ks = 0; ks < 2; ++ks) {
      short8 b = *(const short8*)(wbA + n * H_ + ks * 32 + lg * 8);
      acc[nt] = mfma16(aA[ks], b, acc[nt]);
    }
  }
  f32x4 vacc = fzero;
  {
    int n = lr;
    #pragma unroll
    for (int ks = 0; ks < 2; ++ks) {
      short8 b = *(const short8*)(wbC + n * H_ + ks * 32 + lg * 8);
      vacc = mfma16(aC[ks], b, vacc);
    }
  }
  #pragma unroll
  for (int nt = 0; nt < 2; ++nt) {
    int n = nt * 16 + lr;
    if (n < A_) {
      float bias = abl[n];
      #pragma unroll
      for (int j = 0; j < 4; ++j)
        ltile[w][(lg * 4 + j) * A_ + n] = acc[nt][j] + bias;
    }
  }
  asm volatile("s_waitcnt lgkmcnt(0)" ::: "memory");
  #pragma unroll
  for (int i = 0; i < 5; ++i) {
    int idx = l + i * 64;
    if (idx < 16 * A_)
      out[r0 * A_ + idx] = ltile[w][idx];
  }
  if (lr == 0) {
    float bias = cbv[0];
    #pragma unroll
    for (int j = 0; j < 4; ++j)
      out[VOFF_ + r0 + lg * 4 + j] = vacc[j] + bias;
  }
}

extern "C" void kernel_launch(void* const* d_in, const int* in_sizes, int n_in,
                              void* d_out, int out_size, void* d_ws, size_t ws_size,
                              hipStream_t stream) {
  const float* obs    = (const float*)d_in[0];
  const float* dones  = (const float*)d_in[1];
  const float* astate = (const float*)d_in[2];
  const float* cstate = (const float*)d_in[3];
  const float* aW1  = (const float*)d_in[4];
  const float* ab1  = (const float*)d_in[5];
  const float* aW2  = (const float*)d_in[6];
  const float* ab2  = (const float*)d_in[7];
  const float* aWih = (const float*)d_in[8];
  const float* aWhh = (const float*)d_in[9];
  const float* abih = (const float*)d_in[10];
  const float* abhh = (const float*)d_in[11];
  const float* aWl  = (const float*)d_in[12];
  const float* abl  = (const float*)d_in[13];
  const float* cW1  = (const float*)d_in[14];
  const float* cb1  = (const float*)d_in[15];
  const float* cW2  = (const float*)d_in[16];
  const float* cb2  = (const float*)d_in[17];
  const float* cWih = (const float*)d_in[18];
  const float* cWhh = (const float*)d_in[19];
  const float* cbih = (const float*)d_in[20];
  const float* cbhh = (const float*)d_in[21];
  const float* cWv  = (const float*)d_in[22];
  const float* cbv  = (const float*)d_in[23];
  ushort* ws = (ushort*)d_ws;
  float* out = (float*)d_out;

  const size_t need = ((size_t)2 * XELEMS + 2 * WBR) * 2;
  if (ws_size < need) {
    hipMemsetAsync(d_out, 0x7F, 16, stream);
    return;
  }

  hipLaunchKernelGGL(prep_kernel, dim3(304), dim3(256), 0, stream,
                     aW1, aW2, aWih, aWhh, aWl, cW1, cW2, cWih, cWhh, cWv, ws);
  hipLaunchKernelGGL(mlp_kernel, dim3(TB_ / 256), dim3(256), 0, stream,
                     obs, ws, ab1, ab2, cb1, cb2, ws);
  hipLaunchKernelGGL(scan_kernel, dim3(128), dim3(512), 0, stream,
                     ws + WBASE, ws, ws, dones, astate, cstate,
                     abih, abhh, cbih, cbhh, out);
  hipLaunchKernelGGL(head_kernel, dim3(TB_ / 64), dim3(256), 0, stream,
                     ws, abl, cbv, out);
}

// Round 19
// 326.644 us; speedup vs baseline: 1.0332x; 1.0025x over previous
//
#include <hip/hip_runtime.h>
#include <hip/hip_bf16.h>

typedef short short8 __attribute__((ext_vector_type(8)));
typedef float f32x4 __attribute__((ext_vector_type(4)));

#define T_ 512
#define B_ 1024
#define D_ 128
#define H_ 64
#define A_ 18
#define TB_ (T_*B_)

#define XELEMS (TB_*H_)
#define WBASE  (2*XELEMS)
#define WBR    38912
#define W1OFF  0
#define W2OFF  8192
#define WIHOFF 12288
#define WHHOFF 24576
#define WHDOFF 36864

#define LOGN  (TB_*A_)
#define VOFF_ LOGN
#define SOFF_ (LOGN + TB_)

#define S1_ (-1.4426950408889634f)
#define S2_ (-2.885390081777927f)

__device__ __forceinline__ ushort f2bf(float f) {
  __hip_bfloat16 h = __float2bfloat16(f);
  return __builtin_bit_cast(ushort, h);
}
__device__ __forceinline__ uint cvt_pk_bf16(float lo, float hi) {
  uint r;
  asm("v_cvt_pk_bf16_f32 %0, %1, %2" : "=v"(r) : "v"(lo), "v"(hi));
  return r;
}
__device__ __forceinline__ ushort cvt1_bf16(float v) {
  return (ushort)(cvt_pk_bf16(v, v) & 0xffffu);
}
__device__ __forceinline__ f32x4 mfma16(short8 a, short8 b, f32x4 c) {
  return __builtin_amdgcn_mfma_f32_16x16x32_bf16(a, b, c, 0, 0, 0);
}

__global__ __launch_bounds__(256) void prep_kernel(
    const float* aW1, const float* aW2, const float* aWih, const float* aWhh, const float* aWl,
    const float* cW1, const float* cW2, const float* cWih, const float* cWhh, const float* cWv,
    ushort* wts) {
  int idx = blockIdx.x * 256 + threadIdx.x;
  if (idx >= 2*WBR) return;
  int br = idx / WBR, off = idx % WBR;
  float v;
  if      (off < W2OFF)  v = (br ? cW1  : aW1 )[off];
  else if (off < WIHOFF) v = (br ? cW2  : aW2 )[off - W2OFF];
  else if (off < WHHOFF) {
    int rel = off - WIHOFF;
    v = (br ? cWih : aWih)[rel];
    v *= (rel < 128*H_) ? S1_ : S2_;
  }
  else if (off < WHDOFF) {
    int rel = off - WHHOFF;
    v = (br ? cWhh : aWhh)[rel];
    v *= (rel < 128*H_) ? S1_ : S2_;
  }
  else {
    int t = off - WHDOFF;
    if (br == 0) v = (t < A_*H_) ? aWl[t] : 0.f;
    else         v = (t < H_)    ? cWv[t] : 0.f;
  }
  wts[WBASE + idx] = f2bf(v);
}

// ---- phase 1: MLP (weights in LDS, persistent 4-tile pipeline) -----------------------
__global__ __launch_bounds__(256) void mlp_kernel(
    const float* __restrict__ obs, const ushort* __restrict__ wts,
    const float* __restrict__ ab1, const float* __restrict__ ab2,
    const float* __restrict__ cb1, const float* __restrict__ cb2,
    ushort* __restrict__ xout) {
  __shared__ __align__(16) ushort htA[4][16 * H_], htC[4][16 * H_];
  __shared__ __align__(16) ushort wlds[24576];
  const int tid = threadIdx.x;
  const int l = tid & 63, w = tid >> 6;
  const int lr = l & 15, lg = l >> 4;
  const int key = lr & 7;
  const long base = (long)blockIdx.x * 256;
  const ushort* wbA = wts + WBASE;
  const ushort* wbC = wts + WBASE + WBR;

  float b1A[4], b1C[4], b2A[4], b2C[4];
  #pragma unroll
  for (int nt = 0; nt < 4; ++nt) {
    int coln = nt * 16 + lr;
    b1A[nt] = ab1[coln]; b1C[nt] = cb1[coln];
    b2A[nt] = ab2[coln]; b2C[nt] = cb2[coln];
  }

  #pragma unroll
  for (int i = 0; i < 12; ++i) {
    int c = tid + i * 256;
    int seg = (c < 1024) ? 0 : (c < 2048) ? 1 : (c < 2560) ? 2 : 3;
    int cbase = (seg == 0) ? 0 : (seg == 1) ? 1024 : (seg == 2) ? 2048 : 2560;
    int off = (c - cbase) * 8;
    int L = (seg < 2) ? 128 : 64;
    int segdst = (seg == 0) ? 0 : (seg == 1) ? 8192 : (seg == 2) ? 16384 : 20480;
    const ushort* src = (seg == 0) ? wbA + W1OFF + off :
                        (seg == 1) ? wbC + W1OFF + off :
                        (seg == 2) ? wbA + W2OFF + off : wbC + W2OFF + off;
    int n = off / L, ci = (off % L) / 8;
    int cis = (ci & ~7) | ((ci & 7) ^ (n & 7));
    *(uint4*)(wlds + segdst + n * L + cis * 8) = *(const uint4*)src;
  }
  __syncthreads();

  auto getW1 = [&](int br, int n, int ks) -> short8 {
    int ci = ks * 4 + lg;
    int cis = (ci & 8) | ((ci & 7) ^ (n & 7));
    return *(const short8*)(wlds + br * 8192 + n * D_ + cis * 8);
  };
  auto getW2 = [&](int br, int n, int ks) -> short8 {
    int ci = ks * 4 + lg;
    int cis = ci ^ (n & 7);
    return *(const short8*)(wlds + 16384 + br * 4096 + n * H_ + cis * 8);
  };

  auto ldobs = [&](int s, float4 (&buf)[8]) {
    const float* op = obs + (base + s * 64 + (long)w * 16 + lr) * D_;
    #pragma unroll
    for (int ks = 0; ks < 4; ++ks) {
      buf[2 * ks]     = *(const float4*)(op + ks * 32 + lg * 8);
      buf[2 * ks + 1] = *(const float4*)(op + ks * 32 + lg * 8 + 4);
    }
  };

  auto compute = [&](int s, float4 (&buf)[8]) {
    short8 af[4];
    #pragma unroll
    for (int ks = 0; ks < 4; ++ks) {
      uint4 u;
      u.x = cvt_pk_bf16(buf[2 * ks].x, buf[2 * ks].y);
      u.y = cvt_pk_bf16(buf[2 * ks].z, buf[2 * ks].w);
      u.z = cvt_pk_bf16(buf[2 * ks + 1].x, buf[2 * ks + 1].y);
      u.w = cvt_pk_bf16(buf[2 * ks + 1].z, buf[2 * ks + 1].w);
      af[ks] = __builtin_bit_cast(short8, u);
    }
    f32x4 aA[4], aC[4];
    #pragma unroll
    for (int nt = 0; nt < 4; ++nt) {
      aA[nt] = f32x4{b1A[nt], b1A[nt], b1A[nt], b1A[nt]};
      aC[nt] = f32x4{b1C[nt], b1C[nt], b1C[nt], b1C[nt]};
    }
    #pragma unroll
    for (int ks = 0; ks < 4; ++ks) {
      #pragma unroll
      for (int nt = 0; nt < 4; ++nt) {
        int n = nt * 16 + lr;
        aA[nt] = mfma16(af[ks], getW1(0, n, ks), aA[nt]);
        aC[nt] = mfma16(af[ks], getW1(1, n, ks), aC[nt]);
      }
    }
    #pragma unroll
    for (int nt = 0; nt < 4; ++nt) {
      int coln = nt * 16 + lr;
      #pragma unroll
      for (int j = 0; j < 4; ++j) {
        int rw = lg * 4 + j;
        int idx = rw * H_ + ((((coln >> 3) ^ (rw & 7))) << 3) + (coln & 7);
        htA[w][idx] = cvt1_bf16(fmaxf(aA[nt][j], 0.f));
        htC[w][idx] = cvt1_bf16(fmaxf(aC[nt][j], 0.f));
      }
    }
    short8 a2A[2], a2C[2];
    #pragma unroll
    for (int ks = 0; ks < 2; ++ks) {
      int c = ks * 4 + lg;
      a2A[ks] = *(const short8*)(&htA[w][lr * H_ + ((c ^ key) << 3)]);
      a2C[ks] = *(const short8*)(&htC[w][lr * H_ + ((c ^ key) << 3)]);
    }
    f32x4 cA[4], cC[4];
    #pragma unroll
    for (int nt = 0; nt < 4; ++nt) {
      cA[nt] = f32x4{b2A[nt], b2A[nt], b2A[nt], b2A[nt]};
      cC[nt] = f32x4{b2C[nt], b2C[nt], b2C[nt], b2C[nt]};
    }
    #pragma unroll
    for (int ks = 0; ks < 2; ++ks) {
      #pragma unroll
      for (int nt = 0; nt < 4; ++nt) {
        int n = nt * 16 + lr;
        cA[nt] = mfma16(a2A[ks], getW2(0, n, ks), cA[nt]);
        cC[nt] = mfma16(a2C[ks], getW2(1, n, ks), cC[nt]);
      }
    }
    #pragma unroll
    for (int nt = 0; nt < 4; ++nt) {
      int coln = nt * 16 + lr;
      #pragma unroll
      for (int j = 0; j < 4; ++j) {
        int rw = lg * 4 + j;
        int idx = rw * H_ + ((((coln >> 3) ^ (rw & 7))) << 3) + (coln & 7);
        htA[w][idx] = cvt1_bf16(fmaxf(cA[nt][j], 0.f));
        htC[w][idx] = cvt1_bf16(fmaxf(cC[nt][j], 0.f));
      }
    }
    {
      long rt = base + s * 64 + (long)w * 16;
      ushort* dpA = xout + (size_t)rt * H_;
      ushort* dpC = xout + (size_t)XELEMS + (size_t)rt * H_;
      #pragma unroll
      for (int i = 0; i < 2; ++i) {
        int id = l + i * 64;
        int rr = id >> 3, cc = id & 7;
        uint4 vA = *(const uint4*)(&htA[w][rr * H_ + ((cc ^ (rr & 7)) << 3)]);
        *(uint4*)(dpA + rr * H_ + (cc << 3)) = vA;
        uint4 vC = *(const uint4*)(&htC[w][rr * H_ + ((cc ^ (rr & 7)) << 3)]);
        *(uint4*)(dpC + rr * H_ + (cc << 3)) = vC;
      }
    }
  };

  float4 bufA[8], bufB[8];
  ldobs(0, bufA);
  ldobs(1, bufB);
  compute(0, bufA);
  ldobs(2, bufA);
  compute(1, bufB);
  ldobs(3, bufB);
  compute(2, bufA);
  compute(3, bufB);
}

// ---- phase 2: GRU scan, producer/consumer; consumers at wave-priority 1 (T5) ---------
__global__ __launch_bounds__(512, 1) void scan_kernel(
    const ushort* __restrict__ wts,
    const ushort* __restrict__ xin,     // load-only view of x region
    ushort* __restrict__ hist,          // store-only view (t-disjoint vs loads)
    const float* __restrict__ dones,
    const float* __restrict__ astate, const float* __restrict__ cstate,
    const float* __restrict__ abih, const float* __restrict__ abhh,
    const float* __restrict__ cbih, const float* __restrict__ cbhh,
    float* __restrict__ out) {
  __shared__ __align__(16) ushort hbuf[2][16 * H_];   // 4KB
  __shared__ __align__(8)  ushort dl16[T_ * 16];      // 16KB
  __shared__ __align__(16) float  preL[2][3][1024];   // 24KB
  __shared__ __align__(8)  uint2  hhist[2][256];      // 4KB
  const int tid = threadIdx.x;
  const int l = tid & 63, w = tid >> 6;
  const int pw = w & 3;
  const int lr = l & 15, lg = l >> 4;
  const int grp = blockIdx.x & 1;
  const int b0 = (blockIdx.x >> 1) * 16;
  const int slot = pw * 64 + ((l & ~7) | ((l ^ (l >> 3)) & 7));
  const int o4 = pw * 16 + lg * 4;

  const ushort* wb = wts + grp * WBR;
  const ushort* xp = xin + (size_t)grp * XELEMS;
  ushort* hp = hist + (size_t)grp * XELEMS;
  const float* bihp = grp ? cbih : abih;
  const float* bhhp = grp ? cbhh : abhh;
  const float* st   = grp ? cstate : astate;

  #pragma unroll
  for (int i = 0; i < 4; ++i) {
    int s = tid + i * 512;
    int t = s >> 2, p = s & 3;
    float4 v = *(const float4*)(dones + (size_t)t * B_ + b0 + p * 4);
    uint lo = (v.x != 0.f ? 1u : 0u) | ((v.y != 0.f ? 1u : 0u) << 16);
    uint hi = (v.z != 0.f ? 1u : 0u) | ((v.w != 0.f ? 1u : 0u) << 16);
    *(uint2*)(&dl16[t * 16 + p * 4]) = uint2{lo, hi};
  }

  // consumer state
  short8 hhW[3][2];
  f32x4 bhnv;
  float h_old[4];
  const int myW = lr * H_ + (((pw * 2 + (lg >> 1)) ^ (lr & 7)) << 3) + (lg & 1) * 4;
  const int rdA = lr * H_ + (((0 + lg) ^ (lr & 7)) << 3);
  const int rdB = lr * H_ + (((4 + lg) ^ (lr & 7)) << 3);

  // producer state
  short8 ihW[3][2];
  f32x4 bs0, bs1, binv;
  short8 pb0[2], pb1[2], pb2[2], pb3[2];

  auto loadx = [&](int t, short8 (&f)[2]) {
    const ushort* p = xp + ((size_t)t * B_ + b0 + lr) * H_;
    f[0] = *(const short8*)(p + lg * 8);
    f[1] = *(const short8*)(p + 32 + lg * 8);
  };
  auto cpre_to = [&](short8 (&xb)[2], int par) {
    f32x4 p0 = bs0, p1 = bs1, p2 = binv;
    p0 = mfma16(ihW[0][0], xb[0], p0); p0 = mfma16(ihW[0][1], xb[1], p0);
    p1 = mfma16(ihW[1][0], xb[0], p1); p1 = mfma16(ihW[1][1], xb[1], p1);
    p2 = mfma16(ihW[2][0], xb[0], p2); p2 = mfma16(ihW[2][1], xb[1], p2);
    *(f32x4*)&preL[par][0][slot * 4] = p0;
    *(f32x4*)&preL[par][1][slot * 4] = p1;
    *(f32x4*)&preL[par][2][slot * 4] = p2;
  };

  if (w < 4) {
    #pragma unroll
    for (int g = 0; g < 3; ++g) {
      int n = g * 64 + pw * 16 + lr;
      #pragma unroll
      for (int ks = 0; ks < 2; ++ks)
        hhW[g][ks] = *(const short8*)(wb + WHHOFF + n * H_ + ks * 32 + lg * 8);
    }
    float4 h2v = *(const float4*)(bhhp + 128 + o4);
    bhnv[0] = S2_ * h2v.x; bhnv[1] = S2_ * h2v.y;
    bhnv[2] = S2_ * h2v.z; bhnv[3] = S2_ * h2v.w;
    float4 h0v = *(const float4*)(st + (size_t)(b0 + lr) * H_ + o4);
    bool rs0 = (dones[b0 + lr] != 0.f);
    h_old[0] = rs0 ? 0.f : h0v.x; h_old[1] = rs0 ? 0.f : h0v.y;
    h_old[2] = rs0 ? 0.f : h0v.z; h_old[3] = rs0 ? 0.f : h0v.w;
    uint2 hv;
    hv.x = cvt_pk_bf16(h_old[0], h_old[1]);
    hv.y = cvt_pk_bf16(h_old[2], h_old[3]);
    *(uint2*)(&hbuf[0][myW]) = hv;
  } else {
    #pragma unroll
    for (int g = 0; g < 3; ++g) {
      int n = g * 64 + pw * 16 + lr;
      #pragma unroll
      for (int ks = 0; ks < 2; ++ks)
        ihW[g][ks] = *(const short8*)(wb + WIHOFF + n * H_ + ks * 32 + lg * 8);
    }
    float4 a0 = *(const float4*)(bihp + o4),       h0v = *(const float4*)(bhhp + o4);
    float4 a1 = *(const float4*)(bihp + 64 + o4),  h1v = *(const float4*)(bhhp + 64 + o4);
    float4 a2 = *(const float4*)(bihp + 128 + o4);
    bs0[0]=S1_*(a0.x+h0v.x); bs0[1]=S1_*(a0.y+h0v.y); bs0[2]=S1_*(a0.z+h0v.z); bs0[3]=S1_*(a0.w+h0v.w);
    bs1[0]=S1_*(a1.x+h1v.x); bs1[1]=S1_*(a1.y+h1v.y); bs1[2]=S1_*(a1.z+h1v.z); bs1[3]=S1_*(a1.w+h1v.w);
    binv[0]=S2_*a2.x; binv[1]=S2_*a2.y; binv[2]=S2_*a2.z; binv[3]=S2_*a2.w;
    loadx(0, pb0);
    cpre_to(pb0, 0);
    loadx(1, pb1); loadx(2, pb2); loadx(3, pb3); loadx(4, pb0);
  }

  __syncthreads();

  if (w < 4) {
    // =============================== consumer ===============================
    __builtin_amdgcn_s_setprio(1);   // T5: consumer wins issue arbitration vs producer
    int cur = 0;
    auto cstep = [&](int t) {
      short8 hf0 = *(const short8*)(&hbuf[cur][rdA]);
      short8 hf1 = *(const short8*)(&hbuf[cur][rdB]);
      int par = t & 1;
      f32x4 S0 = *(const f32x4*)&preL[par][0][slot * 4];
      f32x4 S1 = *(const f32x4*)&preL[par][1][slot * 4];
      f32x4 P2 = *(const f32x4*)&preL[par][2][slot * 4];
      f32x4 Gh = bhnv;
      int tn = t + 1;
      ushort dn = dl16[((tn < T_) ? tn : 0) * 16 + lr];
      bool rs = (tn < T_) && (dn != 0);

      S0 = mfma16(hhW[0][0], hf0, S0); S0 = mfma16(hhW[0][1], hf1, S0);
      S1 = mfma16(hhW[1][0], hf0, S1); S1 = mfma16(hhW[1][1], hf1, S1);
      Gh = mfma16(hhW[2][0], hf0, Gh); Gh = mfma16(hhW[2][1], hf1, Gh);

      float hn[4];
      #pragma unroll
      for (int j = 0; j < 4; ++j) {
        // r = rcp(1+Er); sn = P2 + r*Gh; fused z/n update (exact rewrite):
        // hn = (Ez + h + En*(h-Ez)) / (1 + En + Ez + En*Ez)
        float Er = __builtin_amdgcn_exp2f(S0[j]);
        float rr = __builtin_amdgcn_rcpf(1.f + Er);
        float Ez = __builtin_amdgcn_exp2f(S1[j]);
        float sn = fmaf(rr, Gh[j], P2[j]);
        float En = __builtin_amdgcn_exp2f(sn);
        float num = fmaf(En, h_old[j] - Ez, Ez + h_old[j]);
        float den = fmaf(En, Ez, 1.f + En + Ez);
        hn[j] = num * __builtin_amdgcn_rcpf(den);
      }
      uint2 hv;
      hv.x = cvt_pk_bf16(hn[0], hn[1]);
      hv.y = cvt_pk_bf16(hn[2], hn[3]);
      hhist[par][slot] = hv;                 // pre-reset h_t -> producer history store
      uint2 hz;
      hz.x = rs ? 0u : hv.x;
      hz.y = rs ? 0u : hv.y;
      h_old[0] = rs ? 0.f : hn[0]; h_old[1] = rs ? 0.f : hn[1];
      h_old[2] = rs ? 0.f : hn[2]; h_old[3] = rs ? 0.f : hn[3];
      int nxt = cur ^ 1;
      *(uint2*)(&hbuf[nxt][myW]) = hz;
      asm volatile("s_waitcnt lgkmcnt(0)" ::: "memory");
      __builtin_amdgcn_s_barrier();
      cur = nxt;
    };
    for (int t = 0; t < T_; ++t) cstep(t);
    __builtin_amdgcn_s_setprio(0);
    float4 fs = {h_old[0], h_old[1], h_old[2], h_old[3]};
    *(float4*)(out + SOFF_ + (size_t)grp * (B_ * H_) + (size_t)(b0 + lr) * H_ + o4) = fs;
  } else {
    // =============================== producer ===============================
    auto pstep = [&](int t, short8 (&xb)[2]) {
      if (t > 0) {
        uint2 hv2 = hhist[(t - 1) & 1][slot];
        *(uint2*)(hp + ((size_t)(t - 1) * B_ + b0 + lr) * H_ + o4) = hv2;
      }
      if (t + 1 < T_) cpre_to(xb, (t + 1) & 1);
      if (t + 5 < T_) loadx(t + 5, xb);
      asm volatile("s_waitcnt lgkmcnt(0)" ::: "memory");
      __builtin_amdgcn_s_barrier();
    };
    for (int it = 0; it < T_ / 4; ++it) {
      int t = 4 * it;
      pstep(t,     pb1);
      pstep(t + 1, pb2);
      pstep(t + 2, pb3);
      pstep(t + 3, pb0);
    }
    uint2 hv2 = hhist[(T_ - 1) & 1][slot];
    *(uint2*)(hp + ((size_t)(T_ - 1) * B_ + b0 + lr) * H_ + o4) = hv2;
  }
}

// ---------------- phase 3: heads --------------------------------------------------------
__global__ __launch_bounds__(256) void head_kernel(
    const ushort* __restrict__ ws,
    const float* __restrict__ abl, const float* __restrict__ cbv,
    float* __restrict__ out) {
  __shared__ float ltile[4][16 * A_];
  const int tid = threadIdx.x;
  const int l = tid & 63, w = tid >> 6;
  const int lr = l & 15, lg = l >> 4;
  const long r0 = (long)blockIdx.x * 64 + w * 16;
  const f32x4 fzero = {0.f, 0.f, 0.f, 0.f};

  const ushort* hA = ws + r0 * H_;
  const ushort* hC = ws + XELEMS + r0 * H_;
  short8 aA[2], aC[2];
  #pragma unroll
  for (int ks = 0; ks < 2; ++ks) {
    aA[ks] = *(const short8*)(hA + lr * H_ + ks * 32 + lg * 8);
    aC[ks] = *(const short8*)(hC + lr * H_ + ks * 32 + lg * 8);
  }
  const ushort* wbA = ws + WBASE + WHDOFF;
  const ushort* wbC = ws + WBASE + WBR + WHDOFF;
  f32x4 acc[2];
  acc[0] = fzero; acc[1] = fzero;
  #pragma unroll
  for (int nt = 0; nt < 2; ++nt) {
    int n = nt * 16 + lr;
    #pragma unroll
    for (int ks = 0; ks < 2; ++ks) {
      short8 b = *(const short8*)(wbA + n * H_ + ks * 32 + lg * 8);
      acc[nt] = mfma16(aA[ks], b, acc[nt]);
    }
  }
  f32x4 vacc = fzero;
  {
    int n = lr;
    #pragma unroll
    for (int ks = 0; ks < 2; ++ks) {
      short8 b = *(const short8*)(wbC + n * H_ + ks * 32 + lg * 8);
      vacc = mfma16(aC[ks], b, vacc);
    }
  }
  #pragma unroll
  for (int nt = 0; nt < 2; ++nt) {
    int n = nt * 16 + lr;
    if (n < A_) {
      float bias = abl[n];
      #pragma unroll
      for (int j = 0; j < 4; ++j)
        ltile[w][(lg * 4 + j) * A_ + n] = acc[nt][j] + bias;
    }
  }
  asm volatile("s_waitcnt lgkmcnt(0)" ::: "memory");
  #pragma unroll
  for (int i = 0; i < 5; ++i) {
    int idx = l + i * 64;
    if (idx < 16 * A_)
      out[r0 * A_ + idx] = ltile[w][idx];
  }
  if (lr == 0) {
    float bias = cbv[0];
    #pragma unroll
    for (int j = 0; j < 4; ++j)
      out[VOFF_ + r0 + lg * 4 + j] = vacc[j] + bias;
  }
}

extern "C" void kernel_launch(void* const* d_in, const int* in_sizes, int n_in,
                              void* d_out, int out_size, void* d_ws, size_t ws_size,
                              hipStream_t stream) {
  const float* obs    = (const float*)d_in[0];
  const float* dones  = (const float*)d_in[1];
  const float* astate = (const float*)d_in[2];
  const float* cstate = (const float*)d_in[3];
  const float* aW1  = (const float*)d_in[4];
  const float* ab1  = (const float*)d_in[5];
  const float* aW2  = (const float*)d_in[6];
  const float* ab2  = (const float*)d_in[7];
  const float* aWih = (const float*)d_in[8];
  const float* aWhh = (const float*)d_in[9];
  const float* abih = (const float*)d_in[10];
  const float* abhh = (const float*)d_in[11];
  const float* aWl  = (const float*)d_in[12];
  const float* abl  = (const float*)d_in[13];
  const float* cW1  = (const float*)d_in[14];
  const float* cb1  = (const float*)d_in[15];
  const float* cW2  = (const float*)d_in[16];
  const float* cb2  = (const float*)d_in[17];
  const float* cWih = (const float*)d_in[18];
  const float* cWhh = (const float*)d_in[19];
  const float* cbih = (const float*)d_in[20];
  const float* cbhh = (const float*)d_in[21];
  const float* cWv  = (const float*)d_in[22];
  const float* cbv  = (const float*)d_in[23];
  ushort* ws = (ushort*)d_ws;
  float* out = (float*)d_out;

  const size_t need = ((size_t)2 * XELEMS + 2 * WBR) * 2;
  if (ws_size < need) {
    hipMemsetAsync(d_out, 0x7F, 16, stream);
    return;
  }

  hipLaunchKernelGGL(prep_kernel, dim3(304), dim3(256), 0, stream,
                     aW1, aW2, aWih, aWhh, aWl, cW1, cW2, cWih, cWhh, cWv, ws);
  hipLaunchKernelGGL(mlp_kernel, dim3(TB_ / 256), dim3(256), 0, stream,
                     obs, ws, ab1, ab2, cb1, cb2, ws);
  hipLaunchKernelGGL(scan_kernel, dim3(128), dim3(512), 0, stream,
                     ws + WBASE, ws, ws, dones, astate, cstate,
                     abih, abhh, cbih, cbhh, out);
  hipLaunchKernelGGL(head_kernel, dim3(TB_ / 64), dim3(256), 0, stream,
                     ws, abl, cbv, out);
}